// Round 4
// baseline (262.399 us; speedup 1.0000x reference)
//
#include <hip/hip_runtime.h>

// out[b, i] = in[b, perm[i]]  for b in [0, 131072), i in [0, 1024), fp32.
//
// Persistent, software-pipelined, wave-private version:
//  - grid = 1280 blocks (5/CU on 256 CUs) -> all blocks resident, no
//    residency rounds, ~13 iterations per wave
//  - each wave processes a CONTIGUOUS row pair (2gw, 2gw+1) per iteration
//    (8 KB contiguous read region, 8 KB contiguous write region)
//  - register prefetch of the NEXT pair is issued between the LDS staging
//    and the gather of the current pair -> reads stay in flight
//  - wave-private LDS buffers, zero barriers (in-order DS pipe per wave)

#define NCOLS 1024
#define THREADS 256
#define WPB 4   // waves per block

__global__ __launch_bounds__(THREADS) void
permute_rows_pipe(const float* __restrict__ in,
                  const int* __restrict__ perm,
                  float* __restrict__ out,
                  int batch)
{
    __shared__ float buf[WPB][2][NCOLS];   // 32 KB / block
    const int w = threadIdx.x >> 6;
    const int l = threadIdx.x & 63;

    // 16 gather indices per lane, in registers.
    int4 p[4];
#pragma unroll
    for (int k = 0; k < 4; ++k)
        p[k] = *reinterpret_cast<const int4*>(perm + 256 * k + 4 * l);

    const int gw = blockIdx.x * WPB + w;     // global wave id
    const int nw = gridDim.x * WPB;          // total waves
    const int step = 2 * nw;

    int b = 2 * gw;                          // contiguous pair (b, b+1)
    if (b >= batch) return;

    float* const s0 = buf[w][0];
    float* const s1 = buf[w][1];

    // Prologue: load first pair (8 KB contiguous, 16 B/lane coalesced).
    float4 v[8];
    {
        const float* __restrict__ r = in + (size_t)b * NCOLS;
#pragma unroll
        for (int k = 0; k < 8; ++k)
            v[k] = *reinterpret_cast<const float4*>(r + 256 * k + 4 * l);
    }

    while (b < batch) {
        const int bn = b + step;
        // Clamped prefetch address (last iteration re-reads row b; harmless).
        const int bp = (bn < batch) ? bn : b;

        // ---- stage current pair into wave-private LDS ----
#pragma unroll
        for (int k = 0; k < 4; ++k)
            *reinterpret_cast<float4*>(s0 + 256 * k + 4 * l) = v[k];
#pragma unroll
        for (int k = 0; k < 4; ++k)
            *reinterpret_cast<float4*>(s1 + 256 * k + 4 * l) = v[k + 4];

        // ---- prefetch next pair into registers (overlaps gather+store) ----
        float4 vn[8];
        {
            const float* __restrict__ r = in + (size_t)bp * NCOLS;
#pragma unroll
            for (int k = 0; k < 8; ++k)
                vn[k] = *reinterpret_cast<const float4*>(r + 256 * k + 4 * l);
        }

        // ---- gather from LDS, coalesced float4 stores ----
        float* __restrict__ q = out + (size_t)b * NCOLS;
#pragma unroll
        for (int k = 0; k < 4; ++k) {
            float4 o;
            o.x = s0[p[k].x];
            o.y = s0[p[k].y];
            o.z = s0[p[k].z];
            o.w = s0[p[k].w];
            *reinterpret_cast<float4*>(q + 256 * k + 4 * l) = o;
        }
#pragma unroll
        for (int k = 0; k < 4; ++k) {
            float4 o;
            o.x = s1[p[k].x];
            o.y = s1[p[k].y];
            o.z = s1[p[k].z];
            o.w = s1[p[k].w];
            *reinterpret_cast<float4*>(q + NCOLS + 256 * k + 4 * l) = o;
        }

        // ---- rotate pipeline ----
#pragma unroll
        for (int k = 0; k < 8; ++k)
            v[k] = vn[k];
        b = bn;
    }
}

extern "C" void kernel_launch(void* const* d_in, const int* in_sizes, int n_in,
                              void* d_out, int out_size, void* d_ws, size_t ws_size,
                              hipStream_t stream)
{
    const float* features = (const float*)d_in[0];
    const int*   perm     = (const int*)d_in[1];
    float*       out      = (float*)d_out;

    const int batch = out_size / NCOLS;   // 131072

    const int grid = 1280;   // 5 blocks/CU x 256 CU: fully resident, persistent
    permute_rows_pipe<<<grid, THREADS, 0, stream>>>(features, perm, out, batch);
}

// Round 6
// 184.030 us; speedup vs baseline: 1.4258x; 1.4258x over previous
//
#include <hip/hip_runtime.h>

// out[b, i] = in[b, perm[i]]  for b in [0, 131072), i in [0, 1024), fp32.
//
// R3 structure (proven 203.5 us) + ONE change: nontemporal global loads and
// stores. 1 GB streams through the 32 MB L2 with zero reuse; `nt` bypasses
// L2 retention to cut allocate/evict/writeback churn.
//
//  - wave-private LDS staging, ZERO barriers (in-order per-wave DS pipe)
//  - 2 rows per wave-iteration, 8 float4 loads in flight
//  - perm indices register-resident (int4 x4 per lane)
//  - all global accesses 16 B/lane coalesced
//
// NOTE: __builtin_nontemporal_* requires a NATIVE clang vector type, not
// HIP_vector_type — hence the ext_vector_type alias below.

#define NCOLS 1024
#define THREADS 256
#define WPB 4   // waves per block

typedef float f4 __attribute__((ext_vector_type(4)));

__global__ __launch_bounds__(THREADS) void
permute_rows_nt(const float* __restrict__ in,
                const int* __restrict__ perm,
                float* __restrict__ out,
                int batch)
{
    __shared__ float buf[WPB][2][NCOLS];   // 32 KB per block
    const int w = threadIdx.x >> 6;
    const int l = threadIdx.x & 63;

    // 16 gather indices per lane.
    int4 p[4];
#pragma unroll
    for (int k = 0; k < 4; ++k)
        p[k] = *reinterpret_cast<const int4*>(perm + 256 * k + 4 * l);

    const int gw = blockIdx.x * WPB + w;    // global wave id
    const int nw = gridDim.x * WPB;         // total waves

    float* const s0 = buf[w][0];
    float* const s1 = buf[w][1];

    for (int b = gw; b < batch; b += 2 * nw) {
        const int b2 = b + nw;
        const bool has2 = (b2 < batch);

        // ---- issue all global loads for both rows (nontemporal) ----
        const float* __restrict__ r0 = in + (size_t)b * NCOLS;
        const float* __restrict__ r1 = in + (size_t)(has2 ? b2 : b) * NCOLS;
        f4 v0[4], v1[4];
#pragma unroll
        for (int k = 0; k < 4; ++k)
            v0[k] = __builtin_nontemporal_load(
                        reinterpret_cast<const f4*>(r0 + 256 * k + 4 * l));
#pragma unroll
        for (int k = 0; k < 4; ++k)
            v1[k] = __builtin_nontemporal_load(
                        reinterpret_cast<const f4*>(r1 + 256 * k + 4 * l));

        // ---- stage into this wave's private LDS ----
#pragma unroll
        for (int k = 0; k < 4; ++k)
            *reinterpret_cast<f4*>(s0 + 256 * k + 4 * l) = v0[k];
#pragma unroll
        for (int k = 0; k < 4; ++k)
            *reinterpret_cast<f4*>(s1 + 256 * k + 4 * l) = v1[k];

        // ---- gather (wave-synchronous) ----
        f4 o0[4], o1[4];
#pragma unroll
        for (int k = 0; k < 4; ++k) {
            o0[k].x = s0[p[k].x];
            o0[k].y = s0[p[k].y];
            o0[k].z = s0[p[k].z];
            o0[k].w = s0[p[k].w];
        }
#pragma unroll
        for (int k = 0; k < 4; ++k) {
            o1[k].x = s1[p[k].x];
            o1[k].y = s1[p[k].y];
            o1[k].z = s1[p[k].z];
            o1[k].w = s1[p[k].w];
        }

        // ---- coalesced nontemporal stores ----
        float* __restrict__ q0 = out + (size_t)b * NCOLS;
#pragma unroll
        for (int k = 0; k < 4; ++k)
            __builtin_nontemporal_store(
                o0[k], reinterpret_cast<f4*>(q0 + 256 * k + 4 * l));
        if (has2) {
            float* __restrict__ q1 = out + (size_t)b2 * NCOLS;
#pragma unroll
            for (int k = 0; k < 4; ++k)
                __builtin_nontemporal_store(
                    o1[k], reinterpret_cast<f4*>(q1 + 256 * k + 4 * l));
        }
    }
}

extern "C" void kernel_launch(void* const* d_in, const int* in_sizes, int n_in,
                              void* d_out, int out_size, void* d_ws, size_t ws_size,
                              hipStream_t stream)
{
    const float* features = (const float*)d_in[0];
    const int*   perm     = (const int*)d_in[1];
    float*       out      = (float*)d_out;

    const int batch = out_size / NCOLS;   // 131072

    const int grid = 4096;   // 16384 waves; 8 rows per wave (2 per iteration)
    permute_rows_nt<<<grid, THREADS, 0, stream>>>(features, perm, out, batch);
}